// Round 7
// baseline (175.123 us; speedup 1.0000x reference)
//
#include <hip/hip_runtime.h>
#include <hip/hip_fp16.h>

#define N_NODES 50000
#define N_EDGES 800000
#define D 64
#define LN_EPS 1e-5f
#define CAP 48           // padded CSR slots/node; 8 subs x 6 slots
#define SENT 50000       // sentinel src index -> zeroed xs row
#define PREP_NB ((N_EDGES / 4 + 255) / 256)   // 782 prep blocks
#define GEMM_NB ((N_NODES + 63) / 64)         // 782 gemm blocks
#define CNT_PAD 50048                         // cnt ints (layout pad)
#define XS_ROWS 50008                         // xs rows incl. zero row SENT
#define NCHK 98                               // edge chunks
#define CHSZ 8192                             // edges/chunk (last = 5376); c = e>>13
#define HALF 25000                            // nodes per histogram half-range
#define SC_EB 782                             // scatter edge-blocks (1024 edges each)

typedef unsigned short u16;
typedef unsigned int u32;

// ws layout (all 16B-aligned; harness ws >= 256MB):
//   cnt:  CNT_PAD int       (200192 B)  written by pref_k (degrees, no zero-init needed)
//   xs:   XS_ROWS*D half    (6.4 MB)    fp16(x@W), then scaled by dinv; row SENT = 0
//   pe:   E u32             (3.2 MB)    packed dst|src<<16
//   ssrc: N*CAP u16         (4.8 MB)    slots [0,deg) by scatter; rest never read
//   H:    NCHK*50000 u16    (9.8 MB)    per-chunk histogram -> exclusive chunk-prefix
//   lpos: E u16             (1.6 MB)    per-edge local pos within (chunk,node)

// Block-specialized prep+gemm (both dependency-free):
//   blocks [0,PREP_NB): pack edges to u32 (dst|src<<16)
//   blocks [PREP_NB,+GEMM_NB): xs = fp16(x@W); also writes zero row SENT
__global__ __launch_bounds__(256) void prep_gemm_k(const int* __restrict__ src,
                                                   const int* __restrict__ dst,
                                                   u32* __restrict__ pe,
                                                   const float* __restrict__ x,
                                                   const float* __restrict__ W,
                                                   __half* __restrict__ xs) {
    __shared__ float xlds[D * D];
    int bid = blockIdx.x;
    int tid = threadIdx.x;
    if (bid < PREP_NB) {
        int gid = bid * 256 + tid;
        if (gid < N_EDGES / 4) {
            int4 s = ((const int4*)src)[gid];
            int4 d = ((const int4*)dst)[gid];
            uint4 p;
            p.x = (u32)(u16)d.x | ((u32)(u16)s.x << 16);
            p.y = (u32)(u16)d.y | ((u32)(u16)s.y << 16);
            p.z = (u32)(u16)d.z | ((u32)(u16)s.z << 16);
            p.w = (u32)(u16)d.w | ((u32)(u16)s.w << 16);
            ((uint4*)pe)[gid] = p;
        }
    } else {
        int row0 = (bid - PREP_NB) * 64;
        const float4* xg = (const float4*)(x + (size_t)row0 * D);
        float4* xl4 = (float4*)xlds;
        for (int i = tid; i < D * D / 4; i += 256) {
            int grow = row0 + (i >> 4);            // 16 float4 per row
            xl4[i] = (grow < N_NODES) ? xg[i] : make_float4(0.f, 0.f, 0.f, 0.f);
        }
        int lane = tid & 63;
        float wcol[D];
#pragma unroll
        for (int k = 0; k < D; ++k) wcol[k] = W[k * D + lane];
        __syncthreads();
        int wv = tid >> 6;
        for (int rr = 0; rr < 16; ++rr) {
            int r = wv * 16 + rr;
            int grow = row0 + r;
            if (grow >= N_NODES + 1) break;        // +1: write zero row SENT
            const float4* xr = (const float4*)(xlds + r * D);
            float acc = 0.f;
#pragma unroll
            for (int k4 = 0; k4 < 16; ++k4) {
                float4 xv = xr[k4];
                acc += xv.x * wcol[k4 * 4 + 0];
                acc += xv.y * wcol[k4 * 4 + 1];
                acc += xv.z * wcol[k4 * 4 + 2];
                acc += xv.w * wcol[k4 * 4 + 3];
            }
            xs[(size_t)grow * D + lane] = __float2half(acc);   // acc=0 for SENT row
        }
    }
}

// Counting-sort pass 1: per-(chunk, half-range) LDS histogram. NO global
// atomics (the R2-R6 fill was walled at ~45us by 800K device-scope atomic
// RMWs). Two u16 counters packed per u32 LDS word (counts <= 8192, no
// carry-out). The LDS atomicAdd return IS the edge's local position within
// (chunk,node) -> saved to lpos. block = (chunk c = bid>>1, half r = bid&1).
__global__ __launch_bounds__(256) void hist_k(const u32* __restrict__ pe,
                                              u16* __restrict__ lpos,
                                              u16* __restrict__ H) {
    __shared__ u32 lh[HALF / 2];          // 12500 u32 = 50 KB
    int c = blockIdx.x >> 1;
    int r = blockIdx.x & 1;
    int rlo = r * HALF;
    for (int w = threadIdx.x; w < HALF / 2; w += 256) lh[w] = 0;
    __syncthreads();
    int cbase = c * CHSZ;
    u32* H32 = (u32*)H;
#pragma unroll 4
    for (int i = 0; i < CHSZ / 256; ++i) {
        int e = cbase + threadIdx.x + i * 256;
        if (e < N_EDGES) {
            u32 p = pe[e];
            int t = (int)(p & 0xffffu);
            unsigned tr = (unsigned)(t - rlo);
            if (tr < HALF) {
                u32 addend = (tr & 1) ? 0x10000u : 1u;
                u32 old = atomicAdd(&lh[tr >> 1], addend);
                u32 lp = (tr & 1) ? (old >> 16) : (old & 0xffffu);
                lpos[e] = (u16)lp;
            }
        }
    }
    __syncthreads();
    for (int w = threadIdx.x; w < HALF / 2; w += 256)
        H32[(size_t)c * (HALF) + r * (HALF / 2) + w] = lh[w];   // 25000 words/row
}

// Counting-sort pass 2: exclusive prefix over chunks per node (H[c][n] ->
// start-of-chunk offsets) + total degree -> cnt[n]. Block = 256-node tile.
__global__ __launch_bounds__(256) void pref_k(u16* __restrict__ H,
                                              int* __restrict__ cnt) {
    __shared__ u32 ph[NCHK * 128];        // 98*128*4 = 50176 B
    int n0 = blockIdx.x * 256;
    int wbase = n0 >> 1;
    u32* H32 = (u32*)H;
    for (int idx = threadIdx.x; idx < NCHK * 128; idx += 256) {
        int c = idx >> 7, w = idx & 127;
        int gw = wbase + w;
        ph[idx] = (gw < HALF) ? H32[(size_t)c * HALF + gw] : 0;
    }
    __syncthreads();
    u16* ph16 = (u16*)ph;                 // little-endian: low half = even node
    u32 run = 0;
    for (int c = 0; c < NCHK; ++c) {
        int off = c * 256 + threadIdx.x;
        u32 v = ph16[off];
        ph16[off] = (u16)run;             // exclusive prefix (byte-enable safe)
        run += v;
    }
    int n = n0 + threadIdx.x;
    if (n < N_NODES) cnt[n] = (int)run;
    __syncthreads();
    for (int idx = threadIdx.x; idx < NCHK * 128; idx += 256) {
        int c = idx >> 7, w = idx & 127;
        int gw = wbase + w;
        if (gw < HALF) H32[(size_t)c * HALF + gw] = ph[idx];
    }
}

// Counting-sort pass 3 (atomic-free scatter) fused with xs dinv-scale:
//   blocks [0,SC_EB): edge-parallel; pos = start[c][t] + lpos[e]; store ssrc.
//   blocks [SC_EB,..): xs[row] *= rsqrt(cnt[row]+1) (one float4/thread).
__global__ __launch_bounds__(256) void scatter_scale_k(const u32* __restrict__ pe,
                                                       const u16* __restrict__ lpos,
                                                       const u16* __restrict__ H,
                                                       const int* __restrict__ cnt,
                                                       u16* __restrict__ ssrc,
                                                       __half* __restrict__ xs) {
    int bid = blockIdx.x;
    if (bid < SC_EB) {
        int e4 = bid * 1024 + threadIdx.x * 4;
        if (e4 >= N_EDGES) return;
        uint4 p = ((const uint4*)pe)[e4 >> 2];
        ushort4 lp = ((const ushort4*)lpos)[e4 >> 2];
        int c = e4 >> 13;                 // 4-edge group never straddles a chunk
        const u16* st = H + (size_t)c * 50000;
        u32 pp[4] = {p.x, p.y, p.z, p.w};
        u16 ll[4] = {lp.x, lp.y, lp.z, lp.w};
#pragma unroll
        for (int k = 0; k < 4; ++k) {
            int t = (int)(pp[k] & 0xffffu);
            int pos = (int)st[t] + (int)ll[k];
            if (pos < CAP) ssrc[(size_t)t * CAP + pos] = (u16)(pp[k] >> 16);
        }
    } else {
        int gid = (bid - SC_EB) * 256 + threadIdx.x;
        if (gid >= N_NODES * 8) return;
        int row = gid >> 3;
        float di = rsqrtf((float)cnt[row] + 1.0f);
        float4 raw = ((const float4*)xs)[gid];
        __half2* hp = (__half2*)&raw;
#pragma unroll
        for (int i = 0; i < 4; ++i) {
            float2 f = __half22float2(hp[i]);
            hp[i] = __floats2half2_rn(di * f.x, di * f.y);
        }
        ((float4*)xs)[gid] = raw;
    }
}

// wave per node. sub = lane/8 = slot lane, c8 = lane%8 = 8-half column group.
// Degree-adaptive gathers (ns wave-uniform -> exec-skip). Depth-2 chain:
// {cnt, 6x ssrc, x-row} at t0; cndmask slot->SENT; pure gather phase;
// accumulate; fused LN+ReLU. (Unchanged from R6 for clean A/B.)
__global__ __launch_bounds__(256) void agg_ln_k(
        const float* __restrict__ x, const __half* __restrict__ xs,
        const int* __restrict__ cnt, const u16* __restrict__ ssrc,
        const float* __restrict__ b, const float* __restrict__ gamma,
        const float* __restrict__ beta, float* __restrict__ out) {
    int row = blockIdx.x * 4 + (threadIdx.x >> 6);
    if (row >= N_NODES) return;
    int lane = threadIdx.x & 63;
    int sub = lane >> 3;        // 0..7
    int c8  = lane & 7;
    size_t base = (size_t)row * CAP;

    // phase 0: independent loads, all issued before any wait
    int dc = cnt[row];
    int s0 = ssrc[base + sub + 0];
    int s1 = ssrc[base + sub + 8];
    int s2 = ssrc[base + sub + 16];
    int s3 = ssrc[base + sub + 24];
    int s4 = ssrc[base + sub + 32];
    int s5 = ssrc[base + sub + 40];
    const float4* xp = (const float4*)(x + (size_t)row * D + c8 * 8);
    float4 x0 = xp[0], x1 = xp[1];
    float4 xsr = make_float4(0.f, 0.f, 0.f, 0.f);
    if (sub == 0) xsr = *(const float4*)(xs + (size_t)row * D + c8 * 8);  // self-loop

    int deg = dc < CAP ? dc : CAP;
    int ns = (deg + 7) >> 3;    // 0..6, wave-uniform

    // clamp slots beyond deg to the zero SENT row (ssrc there is uninitialized)
    int v0 = (sub +  0 < deg) ? s0 : SENT;
    int v1 = (sub +  8 < deg) ? s1 : SENT;
    int v2 = (sub + 16 < deg) ? s2 : SENT;
    int v3 = (sub + 24 < deg) ? s3 : SENT;
    int v4 = (sub + 32 < deg) ? s4 : SENT;
    int v5 = (sub + 40 < deg) ? s5 : SENT;

    // phase 1: load phase — only the ns needed gathers issue, all in flight
    float4 r0 = make_float4(0.f,0.f,0.f,0.f), r1 = r0, r2 = r0,
           r3 = r0, r4 = r0, r5 = r0;
    if (0 < ns) r0 = *(const float4*)(xs + (size_t)v0 * D + c8 * 8);
    if (1 < ns) r1 = *(const float4*)(xs + (size_t)v1 * D + c8 * 8);
    if (2 < ns) r2 = *(const float4*)(xs + (size_t)v2 * D + c8 * 8);
    if (3 < ns) r3 = *(const float4*)(xs + (size_t)v3 * D + c8 * 8);
    if (4 < ns) r4 = *(const float4*)(xs + (size_t)v4 * D + c8 * 8);
    if (5 < ns) r5 = *(const float4*)(xs + (size_t)v5 * D + c8 * 8);

    float di = rsqrtf((float)dc + 1.0f);   // +1 self-loop

    float4 a0 = make_float4(0.f, 0.f, 0.f, 0.f);
    float4 a1 = make_float4(0.f, 0.f, 0.f, 0.f);
    {
        float4 rr[7] = {r0, r1, r2, r3, r4, r5, xsr};
#pragma unroll
        for (int k = 0; k < 7; ++k) {
            const __half2* hp = (const __half2*)&rr[k];
            float2 p0 = __half22float2(hp[0]), p1 = __half22float2(hp[1]);
            float2 p2 = __half22float2(hp[2]), p3 = __half22float2(hp[3]);
            a0.x += p0.x; a0.y += p0.y; a0.z += p1.x; a0.w += p1.y;
            a1.x += p2.x; a1.y += p2.y; a1.z += p3.x; a1.w += p3.y;
        }
    }

    // reduce over the 8 subs; afterwards every lane holds full sums for its c8 group
#pragma unroll
    for (int o = 8; o < 64; o <<= 1) {
        a0.x += __shfl_xor(a0.x, o, 64); a0.y += __shfl_xor(a0.y, o, 64);
        a0.z += __shfl_xor(a0.z, o, 64); a0.w += __shfl_xor(a0.w, o, 64);
        a1.x += __shfl_xor(a1.x, o, 64); a1.y += __shfl_xor(a1.y, o, 64);
        a1.z += __shfl_xor(a1.z, o, 64); a1.w += __shfl_xor(a1.w, o, 64);
    }

    const float4* bp = (const float4*)(b + c8 * 8);
    float4 b0 = bp[0], b1 = bp[1];

    float h[8];
    h[0] = x0.x + di * a0.x + b0.x;
    h[1] = x0.y + di * a0.y + b0.y;
    h[2] = x0.z + di * a0.z + b0.z;
    h[3] = x0.w + di * a0.w + b0.w;
    h[4] = x1.x + di * a1.x + b1.x;
    h[5] = x1.y + di * a1.y + b1.y;
    h[6] = x1.z + di * a1.z + b1.z;
    h[7] = x1.w + di * a1.w + b1.w;

    // LayerNorm: each column appears once per sub => divisor D*8 = 512
    float s_ = 0.f;
#pragma unroll
    for (int i = 0; i < 8; ++i) s_ += h[i];
#pragma unroll
    for (int o = 1; o < 64; o <<= 1) s_ += __shfl_xor(s_, o, 64);
    float mu = s_ * (1.0f / 512.0f);
    float v_ = 0.f;
    float dd[8];
#pragma unroll
    for (int i = 0; i < 8; ++i) { dd[i] = h[i] - mu; v_ += dd[i] * dd[i]; }
#pragma unroll
    for (int o = 1; o < 64; o <<= 1) v_ += __shfl_xor(v_, o, 64);
    float rstd = rsqrtf(v_ * (1.0f / 512.0f) + LN_EPS);

    if (sub == 0) {
        const float4* gp = (const float4*)(gamma + c8 * 8);
        const float4* ep = (const float4*)(beta + c8 * 8);
        float4 g0 = gp[0], g1 = gp[1];
        float4 e0 = ep[0], e1 = ep[1];
        float4 w0, w1;
        w0.x = fmaxf(dd[0] * rstd * g0.x + e0.x, 0.f);
        w0.y = fmaxf(dd[1] * rstd * g0.y + e0.y, 0.f);
        w0.z = fmaxf(dd[2] * rstd * g0.z + e0.z, 0.f);
        w0.w = fmaxf(dd[3] * rstd * g0.w + e0.w, 0.f);
        w1.x = fmaxf(dd[4] * rstd * g1.x + e1.x, 0.f);
        w1.y = fmaxf(dd[5] * rstd * g1.y + e1.y, 0.f);
        w1.z = fmaxf(dd[6] * rstd * g1.z + e1.z, 0.f);
        w1.w = fmaxf(dd[7] * rstd * g1.w + e1.w, 0.f);
        float4* op = (float4*)(out + (size_t)row * D + c8 * 8);
        op[0] = w0;
        op[1] = w1;
    }
}

extern "C" void kernel_launch(void* const* d_in, const int* in_sizes, int n_in,
                              void* d_out, int out_size, void* d_ws, size_t ws_size,
                              hipStream_t stream) {
    const float* x     = (const float*)d_in[0];
    const int*   ei    = (const int*)d_in[1];
    const float* W     = (const float*)d_in[2];
    const float* b     = (const float*)d_in[3];
    const float* gamma = (const float*)d_in[4];
    const float* beta  = (const float*)d_in[5];
    float* out = (float*)d_out;

    const int* src = ei;
    const int* dst = ei + N_EDGES;

    int*    cnt  = (int*)d_ws;                              // CNT_PAD int
    __half* xs   = (__half*)(cnt + CNT_PAD);                // XS_ROWS*D half
    u32*    pe   = (u32*)(xs + (size_t)XS_ROWS * D);        // E u32
    u16*    ssrc = (u16*)(pe + N_EDGES);                    // N*CAP u16
    u16*    H    = ssrc + (size_t)N_NODES * CAP;            // NCHK*50000 u16
    u16*    lpos = H + (size_t)NCHK * 50000;                // E u16

    prep_gemm_k<<<PREP_NB + GEMM_NB, 256, 0, stream>>>(src, dst, pe, x, W, xs);
    hist_k<<<NCHK * 2, 256, 0, stream>>>(pe, lpos, H);
    pref_k<<<(N_NODES + 255) / 256, 256, 0, stream>>>(H, cnt);
    scatter_scale_k<<<SC_EB + (N_NODES * 8 + 255) / 256, 256, 0, stream>>>(
        pe, lpos, H, cnt, ssrc, xs);
    agg_ln_k<<<(N_NODES + 3) / 4, 256, 0, stream>>>(x, xs, cnt, ssrc, b, gamma, beta, out);
}

// Round 9
// 164.833 us; speedup vs baseline: 1.0624x; 1.0624x over previous
//
#include <hip/hip_runtime.h>
#include <hip/hip_fp16.h>

#define N_NODES 50000
#define N_EDGES 800000
#define D 64
#define LN_EPS 1e-5f
#define CAP 48           // padded CSR slots/node; 8 subs x 6 slots
#define SENT 50000       // sentinel src index -> zeroed xs row
#define PREP_NB ((N_EDGES / 4 + 255) / 256)   // 782 prep blocks
#define GEMM_NB ((N_NODES + 63) / 64)         // 782 gemm blocks
#define CNT_PAD 50048                         // cnt ints (layout pad)
#define XS_ROWS 50008                         // xs rows incl. zero row SENT
#define NRG 8                                 // node ranges (50000 = 8*6250 exactly)
#define RSPAN2 6250
#define NCH2 64                               // edge chunks (800000 = 64*12500 exactly)
#define CHSZ2 12500
#define SC_EB 782                             // scatter edge-blocks (1024 edges each)

typedef unsigned short u16;
typedef unsigned int u32;

// ws layout (all 16B-aligned; harness ws >= 256MB):
//   cnt:  CNT_PAD int       (200192 B)  degrees, written by pref_k (no zero-init)
//   xs:   XS_ROWS*D half    (6.4 MB)    fp16(x@W), then scaled by dinv; row SENT = 0
//   pe:   E u32             (3.2 MB)    packed dst|src<<16
//   ssrc: N*CAP u16         (4.8 MB)    slots [0,deg) by scatter; rest never read
//   H:    NCH2*50000 u16    (6.4 MB)    per-chunk counts -> exclusive chunk-prefix
//   lpos: E u16             (1.6 MB)    per-edge local pos within (chunk,node)
//
// R7 lesson: counting sort v1 failed on PARALLELISM (196 hist blocks, 98-deep
// serial-latency prefix), not concept. v2: 512 hist blocks @25KB LDS,
// prefix loads all 64 chunk values independently (1 latency epoch).
// Zero global atomics anywhere (the R2-R6 atomic fill was ~53us:
// 800K device-scope RMWs at ~7.5/cycle chip-wide coherence wall).

// Block-specialized prep+gemm (both dependency-free):
//   blocks [0,PREP_NB): pack edges to u32 (dst|src<<16)
//   blocks [PREP_NB,+GEMM_NB): xs = fp16(x@W); also writes zero row SENT
__global__ __launch_bounds__(256) void prep_gemm_k(const int* __restrict__ src,
                                                   const int* __restrict__ dst,
                                                   u32* __restrict__ pe,
                                                   const float* __restrict__ x,
                                                   const float* __restrict__ W,
                                                   __half* __restrict__ xs) {
    __shared__ float xlds[D * D];
    int bid = blockIdx.x;
    int tid = threadIdx.x;
    if (bid < PREP_NB) {
        int gid = bid * 256 + tid;
        if (gid < N_EDGES / 4) {
            int4 s = ((const int4*)src)[gid];
            int4 d = ((const int4*)dst)[gid];
            uint4 p;
            p.x = (u32)(u16)d.x | ((u32)(u16)s.x << 16);
            p.y = (u32)(u16)d.y | ((u32)(u16)s.y << 16);
            p.z = (u32)(u16)d.z | ((u32)(u16)s.z << 16);
            p.w = (u32)(u16)d.w | ((u32)(u16)s.w << 16);
            ((uint4*)pe)[gid] = p;
        }
    } else {
        int row0 = (bid - PREP_NB) * 64;
        const float4* xg = (const float4*)(x + (size_t)row0 * D);
        float4* xl4 = (float4*)xlds;
        for (int i = tid; i < D * D / 4; i += 256) {
            int grow = row0 + (i >> 4);            // 16 float4 per row
            xl4[i] = (grow < N_NODES) ? xg[i] : make_float4(0.f, 0.f, 0.f, 0.f);
        }
        int lane = tid & 63;
        float wcol[D];
#pragma unroll
        for (int k = 0; k < D; ++k) wcol[k] = W[k * D + lane];
        __syncthreads();
        int wv = tid >> 6;
        for (int rr = 0; rr < 16; ++rr) {
            int r = wv * 16 + rr;
            int grow = row0 + r;
            if (grow >= N_NODES + 1) break;        // +1: write zero row SENT
            const float4* xr = (const float4*)(xlds + r * D);
            float acc = 0.f;
#pragma unroll
            for (int k4 = 0; k4 < 16; ++k4) {
                float4 xv = xr[k4];
                acc += xv.x * wcol[k4 * 4 + 0];
                acc += xv.y * wcol[k4 * 4 + 1];
                acc += xv.z * wcol[k4 * 4 + 2];
                acc += xv.w * wcol[k4 * 4 + 3];
            }
            xs[(size_t)grow * D + lane] = __float2half(acc);   // acc=0 for SENT row
        }
    }
}

// Counting-sort pass 1: block = (range r = bid&7, chunk c = bid>>3).
// LDS u32 counters over the 6250-node range (25 KB -> 6 blocks/CU, 512
// blocks total). LDS atomicAdd return = edge's local pos within (chunk,
// node) -> lpos[e] (each edge hits exactly one range-block -> no races;
// u16 stores are byte-enabled, no RMW hazard on adjacent halves).
__global__ __launch_bounds__(256) void hist_k(const u32* __restrict__ pe,
                                              u16* __restrict__ lpos,
                                              u16* __restrict__ H) {
    __shared__ u32 lh[RSPAN2];            // 25000 B
    int r = blockIdx.x & (NRG - 1);
    int c = blockIdx.x >> 3;
    int lo = r * RSPAN2;
    for (int w = threadIdx.x; w < RSPAN2; w += 256) lh[w] = 0;
    __syncthreads();
    int cbase = c * CHSZ2;
    for (int i = 0; i < 49; ++i) {        // 49*256 = 12544 >= 12500
        int e = cbase + i * 256 + threadIdx.x;
        if (e < cbase + CHSZ2) {
            u32 p = pe[e];
            unsigned tr = (p & 0xffffu) - (unsigned)lo;
            if (tr < RSPAN2) {
                u32 old = atomicAdd(&lh[tr], 1u);
                lpos[e] = (u16)old;
            }
        }
    }
    __syncthreads();
    // writeback counts: pack u32 pairs -> u32 of 2 x u16 (coalesced)
    u32* H32 = (u32*)(H + (size_t)c * N_NODES + lo);   // lo, N_NODES even
    for (int w = threadIdx.x; w < RSPAN2 / 2; w += 256)
        H32[w] = (lh[2 * w] & 0xffffu) | (lh[2 * w + 1] << 16);
}

// Counting-sort pass 2: one thread per node. All 64 chunk-counts issued as
// INDEPENDENT loads (one latency epoch — the R7 pref was a 98-deep serial
// latency chain), register exclusive-prefix, independent stores. Also
// produces cnt[n] = total degree.
__global__ __launch_bounds__(256) void pref_k(u16* __restrict__ H,
                                              int* __restrict__ cnt) {
    int n = blockIdx.x * 256 + threadIdx.x;
    bool ok = (n < N_NODES);
    u32 v[NCH2];
#pragma unroll
    for (int c = 0; c < NCH2; ++c)
        v[c] = ok ? (u32)H[(size_t)c * N_NODES + n] : 0;
    u32 run = 0;
#pragma unroll
    for (int c = 0; c < NCH2; ++c) { u32 t = v[c]; v[c] = run; run += t; }
    if (ok) {
#pragma unroll
        for (int c = 0; c < NCH2; ++c)
            H[(size_t)c * N_NODES + n] = (u16)v[c];
        cnt[n] = (int)run;
    }
}

// Counting-sort pass 3 (atomic-free scatter) fused with xs dinv-scale:
//   blocks [0,SC_EB): edge-parallel; pos = H[c][t] + lpos[e]; store ssrc.
//     c = e4/12500 is uniform per uint4 group (12500 % 4 == 0, no straddle).
//   blocks [SC_EB,..): xs[row] *= rsqrt(cnt[row]+1) (one float4/thread).
__global__ __launch_bounds__(256) void scatter_scale_k(const u32* __restrict__ pe,
                                                       const u16* __restrict__ lpos,
                                                       const u16* __restrict__ H,
                                                       const int* __restrict__ cnt,
                                                       u16* __restrict__ ssrc,
                                                       __half* __restrict__ xs) {
    int bid = blockIdx.x;
    if (bid < SC_EB) {
        int e4 = bid * 1024 + threadIdx.x * 4;
        if (e4 >= N_EDGES) return;
        uint4 p = ((const uint4*)pe)[e4 >> 2];
        ushort4 lp = ((const ushort4*)lpos)[e4 >> 2];
        int c = e4 / CHSZ2;
        const u16* st = H + (size_t)c * N_NODES;
        u32 pp[4] = {p.x, p.y, p.z, p.w};
        u16 ll[4] = {lp.x, lp.y, lp.z, lp.w};
#pragma unroll
        for (int k = 0; k < 4; ++k) {
            int t = (int)(pp[k] & 0xffffu);
            int pos = (int)st[t] + (int)ll[k];
            if (pos < CAP) ssrc[(size_t)t * CAP + pos] = (u16)(pp[k] >> 16);
        }
    } else {
        int gid = (bid - SC_EB) * 256 + threadIdx.x;
        if (gid >= N_NODES * 8) return;
        int row = gid >> 3;
        float di = rsqrtf((float)cnt[row] + 1.0f);
        float4 raw = ((const float4*)xs)[gid];
        __half2* hp = (__half2*)&raw;
#pragma unroll
        for (int i = 0; i < 4; ++i) {
            float2 f = __half22float2(hp[i]);
            hp[i] = __floats2half2_rn(di * f.x, di * f.y);
        }
        ((float4*)xs)[gid] = raw;
    }
}

// wave per node. sub = lane/8 = slot lane, c8 = lane%8 = 8-half column group.
// Degree-adaptive gathers (ns wave-uniform -> exec-skip). Depth-2 chain:
// {cnt, 6x ssrc, x-row} at t0; cndmask slot->SENT; pure gather phase;
// accumulate; fused LN+ReLU. (Unchanged from R6 for clean A/B.)
__global__ __launch_bounds__(256) void agg_ln_k(
        const float* __restrict__ x, const __half* __restrict__ xs,
        const int* __restrict__ cnt, const u16* __restrict__ ssrc,
        const float* __restrict__ b, const float* __restrict__ gamma,
        const float* __restrict__ beta, float* __restrict__ out) {
    int row = blockIdx.x * 4 + (threadIdx.x >> 6);
    if (row >= N_NODES) return;
    int lane = threadIdx.x & 63;
    int sub = lane >> 3;        // 0..7
    int c8  = lane & 7;
    size_t base = (size_t)row * CAP;

    // phase 0: independent loads, all issued before any wait
    int dc = cnt[row];
    int s0 = ssrc[base + sub + 0];
    int s1 = ssrc[base + sub + 8];
    int s2 = ssrc[base + sub + 16];
    int s3 = ssrc[base + sub + 24];
    int s4 = ssrc[base + sub + 32];
    int s5 = ssrc[base + sub + 40];
    const float4* xp = (const float4*)(x + (size_t)row * D + c8 * 8);
    float4 x0 = xp[0], x1 = xp[1];
    float4 xsr = make_float4(0.f, 0.f, 0.f, 0.f);
    if (sub == 0) xsr = *(const float4*)(xs + (size_t)row * D + c8 * 8);  // self-loop

    int deg = dc < CAP ? dc : CAP;
    int ns = (deg + 7) >> 3;    // 0..6, wave-uniform

    // clamp slots beyond deg to the zero SENT row (ssrc there is uninitialized)
    int v0 = (sub +  0 < deg) ? s0 : SENT;
    int v1 = (sub +  8 < deg) ? s1 : SENT;
    int v2 = (sub + 16 < deg) ? s2 : SENT;
    int v3 = (sub + 24 < deg) ? s3 : SENT;
    int v4 = (sub + 32 < deg) ? s4 : SENT;
    int v5 = (sub + 40 < deg) ? s5 : SENT;

    // phase 1: load phase — only the ns needed gathers issue, all in flight
    float4 r0 = make_float4(0.f,0.f,0.f,0.f), r1 = r0, r2 = r0,
           r3 = r0, r4 = r0, r5 = r0;
    if (0 < ns) r0 = *(const float4*)(xs + (size_t)v0 * D + c8 * 8);
    if (1 < ns) r1 = *(const float4*)(xs + (size_t)v1 * D + c8 * 8);
    if (2 < ns) r2 = *(const float4*)(xs + (size_t)v2 * D + c8 * 8);
    if (3 < ns) r3 = *(const float4*)(xs + (size_t)v3 * D + c8 * 8);
    if (4 < ns) r4 = *(const float4*)(xs + (size_t)v4 * D + c8 * 8);
    if (5 < ns) r5 = *(const float4*)(xs + (size_t)v5 * D + c8 * 8);

    float di = rsqrtf((float)dc + 1.0f);   // +1 self-loop

    float4 a0 = make_float4(0.f, 0.f, 0.f, 0.f);
    float4 a1 = make_float4(0.f, 0.f, 0.f, 0.f);
    {
        float4 rr[7] = {r0, r1, r2, r3, r4, r5, xsr};
#pragma unroll
        for (int k = 0; k < 7; ++k) {
            const __half2* hp = (const __half2*)&rr[k];
            float2 p0 = __half22float2(hp[0]), p1 = __half22float2(hp[1]);
            float2 p2 = __half22float2(hp[2]), p3 = __half22float2(hp[3]);
            a0.x += p0.x; a0.y += p0.y; a0.z += p1.x; a0.w += p1.y;
            a1.x += p2.x; a1.y += p2.y; a1.z += p3.x; a1.w += p3.y;
        }
    }

    // reduce over the 8 subs; afterwards every lane holds full sums for its c8 group
#pragma unroll
    for (int o = 8; o < 64; o <<= 1) {
        a0.x += __shfl_xor(a0.x, o, 64); a0.y += __shfl_xor(a0.y, o, 64);
        a0.z += __shfl_xor(a0.z, o, 64); a0.w += __shfl_xor(a0.w, o, 64);
        a1.x += __shfl_xor(a1.x, o, 64); a1.y += __shfl_xor(a1.y, o, 64);
        a1.z += __shfl_xor(a1.z, o, 64); a1.w += __shfl_xor(a1.w, o, 64);
    }

    const float4* bp = (const float4*)(b + c8 * 8);
    float4 b0 = bp[0], b1 = bp[1];

    float h[8];
    h[0] = x0.x + di * a0.x + b0.x;
    h[1] = x0.y + di * a0.y + b0.y;
    h[2] = x0.z + di * a0.z + b0.z;
    h[3] = x0.w + di * a0.w + b0.w;
    h[4] = x1.x + di * a1.x + b1.x;
    h[5] = x1.y + di * a1.y + b1.y;
    h[6] = x1.z + di * a1.z + b1.z;
    h[7] = x1.w + di * a1.w + b1.w;

    // LayerNorm: each column appears once per sub => divisor D*8 = 512
    float s_ = 0.f;
#pragma unroll
    for (int i = 0; i < 8; ++i) s_ += h[i];
#pragma unroll
    for (int o = 1; o < 64; o <<= 1) s_ += __shfl_xor(s_, o, 64);
    float mu = s_ * (1.0f / 512.0f);
    float v_ = 0.f;
    float dd[8];
#pragma unroll
    for (int i = 0; i < 8; ++i) { dd[i] = h[i] - mu; v_ += dd[i] * dd[i]; }
#pragma unroll
    for (int o = 1; o < 64; o <<= 1) v_ += __shfl_xor(v_, o, 64);
    float rstd = rsqrtf(v_ * (1.0f / 512.0f) + LN_EPS);

    if (sub == 0) {
        const float4* gp = (const float4*)(gamma + c8 * 8);
        const float4* ep = (const float4*)(beta + c8 * 8);
        float4 g0 = gp[0], g1 = gp[1];
        float4 e0 = ep[0], e1 = ep[1];
        float4 w0, w1;
        w0.x = fmaxf(dd[0] * rstd * g0.x + e0.x, 0.f);
        w0.y = fmaxf(dd[1] * rstd * g0.y + e0.y, 0.f);
        w0.z = fmaxf(dd[2] * rstd * g0.z + e0.z, 0.f);
        w0.w = fmaxf(dd[3] * rstd * g0.w + e0.w, 0.f);
        w1.x = fmaxf(dd[4] * rstd * g1.x + e1.x, 0.f);
        w1.y = fmaxf(dd[5] * rstd * g1.y + e1.y, 0.f);
        w1.z = fmaxf(dd[6] * rstd * g1.z + e1.z, 0.f);
        w1.w = fmaxf(dd[7] * rstd * g1.w + e1.w, 0.f);
        float4* op = (float4*)(out + (size_t)row * D + c8 * 8);
        op[0] = w0;
        op[1] = w1;
    }
}

extern "C" void kernel_launch(void* const* d_in, const int* in_sizes, int n_in,
                              void* d_out, int out_size, void* d_ws, size_t ws_size,
                              hipStream_t stream) {
    const float* x     = (const float*)d_in[0];
    const int*   ei    = (const int*)d_in[1];
    const float* W     = (const float*)d_in[2];
    const float* b     = (const float*)d_in[3];
    const float* gamma = (const float*)d_in[4];
    const float* beta  = (const float*)d_in[5];
    float* out = (float*)d_out;

    const int* src = ei;
    const int* dst = ei + N_EDGES;

    int*    cnt  = (int*)d_ws;                              // CNT_PAD int
    __half* xs   = (__half*)(cnt + CNT_PAD);                // XS_ROWS*D half
    u32*    pe   = (u32*)(xs + (size_t)XS_ROWS * D);        // E u32
    u16*    ssrc = (u16*)(pe + N_EDGES);                    // N*CAP u16
    u16*    H    = ssrc + (size_t)N_NODES * CAP;            // NCH2*50000 u16
    u16*    lpos = H + (size_t)NCH2 * N_NODES;              // E u16

    prep_gemm_k<<<PREP_NB + GEMM_NB, 256, 0, stream>>>(src, dst, pe, x, W, xs);
    hist_k<<<NRG * NCH2, 256, 0, stream>>>(pe, lpos, H);
    pref_k<<<(N_NODES + 255) / 256, 256, 0, stream>>>(H, cnt);
    scatter_scale_k<<<SC_EB + (N_NODES * 8 + 255) / 256, 256, 0, stream>>>(
        pe, lpos, H, cnt, ssrc, xs);
    agg_ln_k<<<(N_NODES + 3) / 4, 256, 0, stream>>>(x, xs, cnt, ssrc, b, gamma, beta, out);
}

// Round 10
// 163.027 us; speedup vs baseline: 1.0742x; 1.0111x over previous
//
#include <hip/hip_runtime.h>
#include <hip/hip_fp16.h>

#define N_NODES 50000
#define N_EDGES 800000
#define D 64
#define LN_EPS 1e-5f
#define CAP 48           // padded CSR slots/node; 8 subs x 6 slots
#define SENT 50000       // sentinel src index -> zeroed xs row
#define CNT_PAD 50048                         // cnt ints (layout pad)
#define XS_ROWS 50008                         // xs rows incl. zero row SENT
#define NRG 8                                 // node ranges (50000 = 8*6250)
#define RSPAN2 6250
#define NCH2 64                               // edge chunks (800000 = 64*12500)
#define CHSZ2 12500
#define HIST_NB (NRG * NCH2)                  // 512 hist blocks
#define GEMM_NB ((N_NODES + 63) / 64)         // 782 gemm blocks
#define PREP_NB ((N_EDGES / 4 + 255) / 256)   // 782 pack blocks
#define SC_EB 782                             // scatter blocks (1024 edges each)

typedef unsigned short u16;
typedef unsigned int u32;

// ws layout (all 16B-aligned; harness ws >= 256MB):
//   cnt:  CNT_PAD int       degrees, written by pref_scale_k
//   xs:   XS_ROWS*D half    fp16(x@W) -> scaled by dinv; row SENT = 0
//   pe:   E u32             packed dst|src<<16 (consumed by scatter only)
//   H:    NCH2*50000 u16    per-chunk counts -> exclusive chunk-prefix
//   lpos: E u16             per-edge local pos within (chunk,node)
//   ssrc: N*CAP u16         CSR slots [0,deg); rest never read
//
// R9 lesson: 4 different pipelines all land at 163-165us -> per-dispatch
// overhead/gaps dominate, not kernel bodies. This round: 5 -> 4 launches,
// with ALL dependency-free work (pack, gemm, hist-from-dst) in one
// block-specialized kernel so hist latency hides under gemm VALU.

// K1: block-specialized independent work.
//   [0,HIST_NB):        LDS histogram of dst over (range,chunk); lpos = local pos
//   [HIST_NB,+GEMM_NB): xs = fp16(x@W) (+ zero row SENT)
//   [.. ,+PREP_NB):     pack edges to pe = dst|src<<16
__global__ __launch_bounds__(256) void indep_k(const int* __restrict__ src,
                                               const int* __restrict__ dst,
                                               u32* __restrict__ pe,
                                               u16* __restrict__ lpos,
                                               u16* __restrict__ H,
                                               const float* __restrict__ x,
                                               const float* __restrict__ W,
                                               __half* __restrict__ xs) {
    __shared__ u32 smem[RSPAN2];              // 25000 B (gemm uses 16 KB of it)
    int bid = blockIdx.x;
    int tid = threadIdx.x;
    if (bid < HIST_NB) {
        // ---- histogram: r = bid&7 (node range), c = bid>>3 (edge chunk) ----
        int r = bid & (NRG - 1);
        int c = bid >> 3;
        int lo = r * RSPAN2;
        for (int w = tid; w < RSPAN2; w += 256) smem[w] = 0;
        __syncthreads();
        int cbase = c * CHSZ2;
        for (int i = 0; i < 49; ++i) {        // 49*256 = 12544 >= 12500
            int e = cbase + i * 256 + tid;
            if (e < cbase + CHSZ2) {
                unsigned tr = (unsigned)dst[e] - (unsigned)lo;
                if (tr < RSPAN2) {
                    u32 old = atomicAdd(&smem[tr], 1u);
                    lpos[e] = (u16)old;
                }
            }
        }
        __syncthreads();
        u32* H32 = (u32*)(H + (size_t)c * N_NODES + lo);   // lo, N_NODES even
        for (int w = tid; w < RSPAN2 / 2; w += 256)
            H32[w] = (smem[2 * w] & 0xffffu) | (smem[2 * w + 1] << 16);
    } else if (bid < HIST_NB + GEMM_NB) {
        // ---- gemm: xs = fp16(x@W), one 64-row tile/block ----
        float* xlds = (float*)smem;
        int row0 = (bid - HIST_NB) * 64;
        const float4* xg = (const float4*)(x + (size_t)row0 * D);
        float4* xl4 = (float4*)xlds;
        for (int i = tid; i < D * D / 4; i += 256) {
            int grow = row0 + (i >> 4);            // 16 float4 per row
            xl4[i] = (grow < N_NODES) ? xg[i] : make_float4(0.f, 0.f, 0.f, 0.f);
        }
        int lane = tid & 63;
        float wcol[D];
#pragma unroll
        for (int k = 0; k < D; ++k) wcol[k] = W[k * D + lane];
        __syncthreads();
        int wv = tid >> 6;
        for (int rr = 0; rr < 16; ++rr) {
            int rloc = wv * 16 + rr;
            int grow = row0 + rloc;
            if (grow >= N_NODES + 1) break;        // +1: write zero row SENT
            const float4* xr = (const float4*)(xlds + rloc * D);
            float acc = 0.f;
#pragma unroll
            for (int k4 = 0; k4 < 16; ++k4) {
                float4 xv = xr[k4];
                acc += xv.x * wcol[k4 * 4 + 0];
                acc += xv.y * wcol[k4 * 4 + 1];
                acc += xv.z * wcol[k4 * 4 + 2];
                acc += xv.w * wcol[k4 * 4 + 3];
            }
            xs[(size_t)grow * D + lane] = __float2half(acc);   // acc=0 for SENT row
        }
    } else {
        // ---- pack: pe = dst | src<<16, 4 edges/thread ----
        int gid = (bid - HIST_NB - GEMM_NB) * 256 + tid;
        if (gid < N_EDGES / 4) {
            int4 s = ((const int4*)src)[gid];
            int4 d = ((const int4*)dst)[gid];
            uint4 p;
            p.x = (u32)(u16)d.x | ((u32)(u16)s.x << 16);
            p.y = (u32)(u16)d.y | ((u32)(u16)s.y << 16);
            p.z = (u32)(u16)d.z | ((u32)(u16)s.z << 16);
            p.w = (u32)(u16)d.w | ((u32)(u16)s.w << 16);
            ((uint4*)pe)[gid] = p;
        }
    }
}

// K2: per-node chunk-prefix (64 independent loads -> register exclusive
// prefix -> writeback), cnt[n] = degree, THEN block-cooperative coalesced
// dinv-scale of xs rows (dinv broadcast via LDS).
__global__ __launch_bounds__(256) void pref_scale_k(u16* __restrict__ H,
                                                    int* __restrict__ cnt,
                                                    __half* __restrict__ xs) {
    __shared__ float sdi[256];
    int n0 = blockIdx.x * 256;
    int n = n0 + threadIdx.x;
    bool ok = (n < N_NODES);
    u32 v[NCH2];
#pragma unroll
    for (int c = 0; c < NCH2; ++c)
        v[c] = ok ? (u32)H[(size_t)c * N_NODES + n] : 0;
    u32 run = 0;
#pragma unroll
    for (int c = 0; c < NCH2; ++c) { u32 t = v[c]; v[c] = run; run += t; }
    if (ok) {
#pragma unroll
        for (int c = 0; c < NCH2; ++c)
            H[(size_t)c * N_NODES + n] = (u16)v[c];
        cnt[n] = (int)run;
    }
    sdi[threadIdx.x] = rsqrtf((float)run + 1.0f);
    __syncthreads();
    // scale xs rows n0..n0+255: 2048 float4, coalesced (8 float4/row)
    float4* xs4 = (float4*)xs;
#pragma unroll
    for (int j = 0; j < 8; ++j) {
        int idx = threadIdx.x + j * 256;
        int lrow = idx >> 3;
        int row = n0 + lrow;
        if (row < N_NODES) {
            float di = sdi[lrow];
            size_t g4 = (size_t)row * 8 + (idx & 7);
            float4 raw = xs4[g4];
            __half2* hp = (__half2*)&raw;
#pragma unroll
            for (int i = 0; i < 4; ++i) {
                float2 f = __half22float2(hp[i]);
                hp[i] = __floats2half2_rn(di * f.x, di * f.y);
            }
            xs4[g4] = raw;
        }
    }
}

// K3: atomic-free scatter. pos = H[c][t] + lpos[e]; store src u16.
// c = e4/12500 uniform per uint4 group (12500 % 4 == 0, no straddle).
__global__ __launch_bounds__(256) void scatter_k(const u32* __restrict__ pe,
                                                 const u16* __restrict__ lpos,
                                                 const u16* __restrict__ H,
                                                 u16* __restrict__ ssrc) {
    int e4 = blockIdx.x * 1024 + threadIdx.x * 4;
    if (e4 >= N_EDGES) return;
    uint4 p = ((const uint4*)pe)[e4 >> 2];
    ushort4 lp = ((const ushort4*)lpos)[e4 >> 2];
    int c = e4 / CHSZ2;
    const u16* st = H + (size_t)c * N_NODES;
    u32 pp[4] = {p.x, p.y, p.z, p.w};
    u16 ll[4] = {lp.x, lp.y, lp.z, lp.w};
#pragma unroll
    for (int k = 0; k < 4; ++k) {
        int t = (int)(pp[k] & 0xffffu);
        int pos = (int)st[t] + (int)ll[k];
        if (pos < CAP) ssrc[(size_t)t * CAP + pos] = (u16)(pp[k] >> 16);
    }
}

// K4: wave per node. sub = lane/8 = slot lane, c8 = lane%8 = 8-half column
// group. Degree-adaptive gathers (ns wave-uniform -> exec-skip). Depth-2
// chain; fused LN+ReLU. (Unchanged from R6/R9 for clean A/B.)
__global__ __launch_bounds__(256) void agg_ln_k(
        const float* __restrict__ x, const __half* __restrict__ xs,
        const int* __restrict__ cnt, const u16* __restrict__ ssrc,
        const float* __restrict__ b, const float* __restrict__ gamma,
        const float* __restrict__ beta, float* __restrict__ out) {
    int row = blockIdx.x * 4 + (threadIdx.x >> 6);
    if (row >= N_NODES) return;
    int lane = threadIdx.x & 63;
    int sub = lane >> 3;        // 0..7
    int c8  = lane & 7;
    size_t base = (size_t)row * CAP;

    // phase 0: independent loads, all issued before any wait
    int dc = cnt[row];
    int s0 = ssrc[base + sub + 0];
    int s1 = ssrc[base + sub + 8];
    int s2 = ssrc[base + sub + 16];
    int s3 = ssrc[base + sub + 24];
    int s4 = ssrc[base + sub + 32];
    int s5 = ssrc[base + sub + 40];
    const float4* xp = (const float4*)(x + (size_t)row * D + c8 * 8);
    float4 x0 = xp[0], x1 = xp[1];
    float4 xsr = make_float4(0.f, 0.f, 0.f, 0.f);
    if (sub == 0) xsr = *(const float4*)(xs + (size_t)row * D + c8 * 8);  // self-loop

    int deg = dc < CAP ? dc : CAP;
    int ns = (deg + 7) >> 3;    // 0..6, wave-uniform

    // clamp slots beyond deg to the zero SENT row
    int v0 = (sub +  0 < deg) ? s0 : SENT;
    int v1 = (sub +  8 < deg) ? s1 : SENT;
    int v2 = (sub + 16 < deg) ? s2 : SENT;
    int v3 = (sub + 24 < deg) ? s3 : SENT;
    int v4 = (sub + 32 < deg) ? s4 : SENT;
    int v5 = (sub + 40 < deg) ? s5 : SENT;

    // phase 1: only the ns needed gathers issue, all in flight
    float4 r0 = make_float4(0.f,0.f,0.f,0.f), r1 = r0, r2 = r0,
           r3 = r0, r4 = r0, r5 = r0;
    if (0 < ns) r0 = *(const float4*)(xs + (size_t)v0 * D + c8 * 8);
    if (1 < ns) r1 = *(const float4*)(xs + (size_t)v1 * D + c8 * 8);
    if (2 < ns) r2 = *(const float4*)(xs + (size_t)v2 * D + c8 * 8);
    if (3 < ns) r3 = *(const float4*)(xs + (size_t)v3 * D + c8 * 8);
    if (4 < ns) r4 = *(const float4*)(xs + (size_t)v4 * D + c8 * 8);
    if (5 < ns) r5 = *(const float4*)(xs + (size_t)v5 * D + c8 * 8);

    float di = rsqrtf((float)dc + 1.0f);   // +1 self-loop

    float4 a0 = make_float4(0.f, 0.f, 0.f, 0.f);
    float4 a1 = make_float4(0.f, 0.f, 0.f, 0.f);
    {
        float4 rr[7] = {r0, r1, r2, r3, r4, r5, xsr};
#pragma unroll
        for (int k = 0; k < 7; ++k) {
            const __half2* hp = (const __half2*)&rr[k];
            float2 p0 = __half22float2(hp[0]), p1 = __half22float2(hp[1]);
            float2 p2 = __half22float2(hp[2]), p3 = __half22float2(hp[3]);
            a0.x += p0.x; a0.y += p0.y; a0.z += p1.x; a0.w += p1.y;
            a1.x += p2.x; a1.y += p2.y; a1.z += p3.x; a1.w += p3.y;
        }
    }

    // reduce over the 8 subs
#pragma unroll
    for (int o = 8; o < 64; o <<= 1) {
        a0.x += __shfl_xor(a0.x, o, 64); a0.y += __shfl_xor(a0.y, o, 64);
        a0.z += __shfl_xor(a0.z, o, 64); a0.w += __shfl_xor(a0.w, o, 64);
        a1.x += __shfl_xor(a1.x, o, 64); a1.y += __shfl_xor(a1.y, o, 64);
        a1.z += __shfl_xor(a1.z, o, 64); a1.w += __shfl_xor(a1.w, o, 64);
    }

    const float4* bp = (const float4*)(b + c8 * 8);
    float4 b0 = bp[0], b1 = bp[1];

    float h[8];
    h[0] = x0.x + di * a0.x + b0.x;
    h[1] = x0.y + di * a0.y + b0.y;
    h[2] = x0.z + di * a0.z + b0.z;
    h[3] = x0.w + di * a0.w + b0.w;
    h[4] = x1.x + di * a1.x + b1.x;
    h[5] = x1.y + di * a1.y + b1.y;
    h[6] = x1.z + di * a1.z + b1.z;
    h[7] = x1.w + di * a1.w + b1.w;

    // LayerNorm: each column appears once per sub => divisor D*8 = 512
    float s_ = 0.f;
#pragma unroll
    for (int i = 0; i < 8; ++i) s_ += h[i];
#pragma unroll
    for (int o = 1; o < 64; o <<= 1) s_ += __shfl_xor(s_, o, 64);
    float mu = s_ * (1.0f / 512.0f);
    float v_ = 0.f;
    float dd[8];
#pragma unroll
    for (int i = 0; i < 8; ++i) { dd[i] = h[i] - mu; v_ += dd[i] * dd[i]; }
#pragma unroll
    for (int o = 1; o < 64; o <<= 1) v_ += __shfl_xor(v_, o, 64);
    float rstd = rsqrtf(v_ * (1.0f / 512.0f) + LN_EPS);

    if (sub == 0) {
        const float4* gp = (const float4*)(gamma + c8 * 8);
        const float4* ep = (const float4*)(beta + c8 * 8);
        float4 g0 = gp[0], g1 = gp[1];
        float4 e0 = ep[0], e1 = ep[1];
        float4 w0, w1;
        w0.x = fmaxf(dd[0] * rstd * g0.x + e0.x, 0.f);
        w0.y = fmaxf(dd[1] * rstd * g0.y + e0.y, 0.f);
        w0.z = fmaxf(dd[2] * rstd * g0.z + e0.z, 0.f);
        w0.w = fmaxf(dd[3] * rstd * g0.w + e0.w, 0.f);
        w1.x = fmaxf(dd[4] * rstd * g1.x + e1.x, 0.f);
        w1.y = fmaxf(dd[5] * rstd * g1.y + e1.y, 0.f);
        w1.z = fmaxf(dd[6] * rstd * g1.z + e1.z, 0.f);
        w1.w = fmaxf(dd[7] * rstd * g1.w + e1.w, 0.f);
        float4* op = (float4*)(out + (size_t)row * D + c8 * 8);
        op[0] = w0;
        op[1] = w1;
    }
}

extern "C" void kernel_launch(void* const* d_in, const int* in_sizes, int n_in,
                              void* d_out, int out_size, void* d_ws, size_t ws_size,
                              hipStream_t stream) {
    const float* x     = (const float*)d_in[0];
    const int*   ei    = (const int*)d_in[1];
    const float* W     = (const float*)d_in[2];
    const float* b     = (const float*)d_in[3];
    const float* gamma = (const float*)d_in[4];
    const float* beta  = (const float*)d_in[5];
    float* out = (float*)d_out;

    const int* src = ei;
    const int* dst = ei + N_EDGES;

    int*    cnt  = (int*)d_ws;                              // CNT_PAD int
    __half* xs   = (__half*)(cnt + CNT_PAD);                // XS_ROWS*D half
    u32*    pe   = (u32*)(xs + (size_t)XS_ROWS * D);        // E u32
    u16*    H    = (u16*)(pe + N_EDGES);                    // NCH2*50000 u16
    u16*    lpos = H + (size_t)NCH2 * N_NODES;              // E u16
    u16*    ssrc = lpos + N_EDGES;                          // N*CAP u16

    indep_k<<<HIST_NB + GEMM_NB + PREP_NB, 256, 0, stream>>>(
        src, dst, pe, lpos, H, x, W, xs);
    pref_scale_k<<<(N_NODES + 255) / 256, 256, 0, stream>>>(H, cnt, xs);
    scatter_k<<<SC_EB, 256, 0, stream>>>(pe, lpos, H, ssrc);
    agg_ln_k<<<(N_NODES + 3) / 4, 256, 0, stream>>>(x, xs, cnt, ssrc, b, gamma, beta, out);
}

// Round 11
// 154.153 us; speedup vs baseline: 1.1360x; 1.0576x over previous
//
#include <hip/hip_runtime.h>
#include <hip/hip_fp16.h>

#define N_NODES 50000
#define N_EDGES 800000
#define D 64
#define LN_EPS 1e-5f
#define CAP 48           // padded CSR slots/node; 8 subs x 6 slots
#define SENT 50000       // sentinel src index -> zeroed xs row
#define CNT_PAD 50048                         // cnt ints (layout pad)
#define XS_ROWS 50008                         // xs rows incl. zero row SENT
#define NRG 8                                 // node ranges (50000 = 8*6250)
#define RSPAN2 6250
#define NCH2 64                               // edge chunks (800000 = 64*12500)
#define CHSZ2 12500
#define HIST_NB (NRG * NCH2)                  // 512 hist blocks
#define GEMM_NB ((N_NODES + 63) / 64)         // 782 gemm blocks
#define SC_EB 782                             // scatter blocks (1024 edges each)

typedef unsigned short u16;
typedef unsigned int u32;

// ws layout (all 16B-aligned; harness ws >= 256MB):
//   cnt:  CNT_PAD int       degrees, written by pref_scale_k
//   xs:   XS_ROWS*D half    fp16(x@W) -> scaled by dinv; row SENT = 0
//   H:    NCH2*50000 u16    per-chunk counts -> exclusive chunk-prefix
//   lpos: E u16             per-edge local pos within (chunk,node)
//   ssrc: N*CAP u16         CSR slots [0,deg); rest never read
//
// R10 lesson: fused indep_k measured 46.6us at 17.8% occupancy — the 25KB
// static LDS capped ALL blocks at 6/CU, and hist's 49 serial scalar-load
// epochs were the hidden 40us cost all along. This round: u16-packed LDS
// counters (12.5KB; union 16KB with gemm), int4-batched dst scan (13
// epochs), and pe/pack deleted (scatter reads src/dst directly).

// K1: block-specialized independent work.
//   [0,HIST_NB):        LDS histogram of dst over (range,chunk); lpos = local pos
//   [HIST_NB,+GEMM_NB): xs = fp16(x@W) (+ zero row SENT)
__global__ __launch_bounds__(256) void indep_k(const int* __restrict__ dst,
                                               u16* __restrict__ lpos,
                                               u16* __restrict__ H,
                                               const float* __restrict__ x,
                                               const float* __restrict__ W,
                                               __half* __restrict__ xs) {
    __shared__ u32 smem[4096];                // 16384 B (hist uses 12.5KB of it)
    int bid = blockIdx.x;
    int tid = threadIdx.x;
    if (bid < HIST_NB) {
        // ---- histogram: r = bid&7 (node range), c = bid>>3 (edge chunk) ----
        // u16-pair-packed counters: node tr -> word tr>>1, half tr&1.
        // Max count/chunk = 12500 < 65536: no overflow, no carry-out.
        int r = bid & (NRG - 1);
        int c = bid >> 3;
        int lo = r * RSPAN2;
        for (int w = tid; w < RSPAN2 / 2; w += 256) smem[w] = 0;
        __syncthreads();
        int cbase = c * CHSZ2;
        const int4* d4 = (const int4*)(dst + cbase);   // 50000 B/chunk, 16B-aligned
#pragma unroll
        for (int i = 0; i < 13; ++i) {        // 13*256 = 3328 >= 3125 int4
            int g = i * 256 + tid;
            if (g < CHSZ2 / 4) {
                int4 dv = d4[g];
                int e = cbase + g * 4;
                int dd[4] = {dv.x, dv.y, dv.z, dv.w};
#pragma unroll
                for (int k = 0; k < 4; ++k) {
                    unsigned tr = (unsigned)dd[k] - (unsigned)lo;
                    if (tr < RSPAN2) {
                        u32 addend = (tr & 1) ? 0x10000u : 1u;
                        u32 old = atomicAdd(&smem[tr >> 1], addend);
                        lpos[e + k] = (u16)((tr & 1) ? (old >> 16) : (old & 0xffffu));
                    }
                }
            }
        }
        __syncthreads();
        // counts already u16-packed: direct copy (12500 B/row slice)
        u32* H32 = (u32*)(H + (size_t)c * N_NODES + lo);
        for (int w = tid; w < RSPAN2 / 2; w += 256)
            H32[w] = smem[w];
    } else {
        // ---- gemm: xs = fp16(x@W), one 64-row tile/block ----
        float* xlds = (float*)smem;
        int row0 = (bid - HIST_NB) * 64;
        const float4* xg = (const float4*)(x + (size_t)row0 * D);
        float4* xl4 = (float4*)xlds;
        for (int i = tid; i < D * D / 4; i += 256) {
            int grow = row0 + (i >> 4);            // 16 float4 per row
            xl4[i] = (grow < N_NODES) ? xg[i] : make_float4(0.f, 0.f, 0.f, 0.f);
        }
        int lane = tid & 63;
        float wcol[D];
#pragma unroll
        for (int k = 0; k < D; ++k) wcol[k] = W[k * D + lane];
        __syncthreads();
        int wv = tid >> 6;
        for (int rr = 0; rr < 16; ++rr) {
            int rloc = wv * 16 + rr;
            int grow = row0 + rloc;
            if (grow >= N_NODES + 1) break;        // +1: write zero row SENT
            const float4* xr = (const float4*)(xlds + rloc * D);
            float acc = 0.f;
#pragma unroll
            for (int k4 = 0; k4 < 16; ++k4) {
                float4 xv = xr[k4];
                acc += xv.x * wcol[k4 * 4 + 0];
                acc += xv.y * wcol[k4 * 4 + 1];
                acc += xv.z * wcol[k4 * 4 + 2];
                acc += xv.w * wcol[k4 * 4 + 3];
            }
            xs[(size_t)grow * D + lane] = __float2half(acc);   // acc=0 for SENT row
        }
    }
}

// K2: per-node chunk-prefix (64 independent loads -> register exclusive
// prefix -> writeback), cnt[n] = degree, THEN block-cooperative coalesced
// dinv-scale of xs rows (dinv broadcast via LDS).
__global__ __launch_bounds__(256) void pref_scale_k(u16* __restrict__ H,
                                                    int* __restrict__ cnt,
                                                    __half* __restrict__ xs) {
    __shared__ float sdi[256];
    int n0 = blockIdx.x * 256;
    int n = n0 + threadIdx.x;
    bool ok = (n < N_NODES);
    u32 v[NCH2];
#pragma unroll
    for (int c = 0; c < NCH2; ++c)
        v[c] = ok ? (u32)H[(size_t)c * N_NODES + n] : 0;
    u32 run = 0;
#pragma unroll
    for (int c = 0; c < NCH2; ++c) { u32 t = v[c]; v[c] = run; run += t; }
    if (ok) {
#pragma unroll
        for (int c = 0; c < NCH2; ++c)
            H[(size_t)c * N_NODES + n] = (u16)v[c];
        cnt[n] = (int)run;
    }
    sdi[threadIdx.x] = rsqrtf((float)run + 1.0f);
    __syncthreads();
    // scale xs rows n0..n0+255: 2048 float4, coalesced (8 float4/row)
    float4* xs4 = (float4*)xs;
#pragma unroll
    for (int j = 0; j < 8; ++j) {
        int idx = threadIdx.x + j * 256;
        int lrow = idx >> 3;
        int row = n0 + lrow;
        if (row < N_NODES) {
            float di = sdi[lrow];
            size_t g4 = (size_t)row * 8 + (idx & 7);
            float4 raw = xs4[g4];
            __half2* hp = (__half2*)&raw;
#pragma unroll
            for (int i = 0; i < 4; ++i) {
                float2 f = __half22float2(hp[i]);
                hp[i] = __floats2half2_rn(di * f.x, di * f.y);
            }
            xs4[g4] = raw;
        }
    }
}

// K3: atomic-free scatter, straight from src/dst (pe/pack deleted).
// pos = H[c][t] + lpos[e]; store src u16. c = e4/12500 uniform per
// int4 group (12500 % 4 == 0, no straddle).
__global__ __launch_bounds__(256) void scatter_k(const int* __restrict__ src,
                                                 const int* __restrict__ dst,
                                                 const u16* __restrict__ lpos,
                                                 const u16* __restrict__ H,
                                                 u16* __restrict__ ssrc) {
    int e4 = blockIdx.x * 1024 + threadIdx.x * 4;
    if (e4 >= N_EDGES) return;
    int4 dv = ((const int4*)dst)[e4 >> 2];
    int4 sv = ((const int4*)src)[e4 >> 2];
    ushort4 lp = ((const ushort4*)lpos)[e4 >> 2];
    int c = e4 / CHSZ2;
    const u16* st = H + (size_t)c * N_NODES;
    int td[4] = {dv.x, dv.y, dv.z, dv.w};
    int ts[4] = {sv.x, sv.y, sv.z, sv.w};
    u16 ll[4] = {lp.x, lp.y, lp.z, lp.w};
#pragma unroll
    for (int k = 0; k < 4; ++k) {
        int t = td[k];
        int pos = (int)st[t] + (int)ll[k];
        if (pos < CAP) ssrc[(size_t)t * CAP + pos] = (u16)ts[k];
    }
}

// K4: wave per node. sub = lane/8 = slot lane, c8 = lane%8 = 8-half column
// group. Degree-adaptive gathers (ns wave-uniform -> exec-skip). Depth-2
// chain; fused LN+ReLU. (Unchanged from R6/R9/R10 for clean A/B.)
__global__ __launch_bounds__(256) void agg_ln_k(
        const float* __restrict__ x, const __half* __restrict__ xs,
        const int* __restrict__ cnt, const u16* __restrict__ ssrc,
        const float* __restrict__ b, const float* __restrict__ gamma,
        const float* __restrict__ beta, float* __restrict__ out) {
    int row = blockIdx.x * 4 + (threadIdx.x >> 6);
    if (row >= N_NODES) return;
    int lane = threadIdx.x & 63;
    int sub = lane >> 3;        // 0..7
    int c8  = lane & 7;
    size_t base = (size_t)row * CAP;

    // phase 0: independent loads, all issued before any wait
    int dc = cnt[row];
    int s0 = ssrc[base + sub + 0];
    int s1 = ssrc[base + sub + 8];
    int s2 = ssrc[base + sub + 16];
    int s3 = ssrc[base + sub + 24];
    int s4 = ssrc[base + sub + 32];
    int s5 = ssrc[base + sub + 40];
    const float4* xp = (const float4*)(x + (size_t)row * D + c8 * 8);
    float4 x0 = xp[0], x1 = xp[1];
    float4 xsr = make_float4(0.f, 0.f, 0.f, 0.f);
    if (sub == 0) xsr = *(const float4*)(xs + (size_t)row * D + c8 * 8);  // self-loop

    int deg = dc < CAP ? dc : CAP;
    int ns = (deg + 7) >> 3;    // 0..6, wave-uniform

    // clamp slots beyond deg to the zero SENT row
    int v0 = (sub +  0 < deg) ? s0 : SENT;
    int v1 = (sub +  8 < deg) ? s1 : SENT;
    int v2 = (sub + 16 < deg) ? s2 : SENT;
    int v3 = (sub + 24 < deg) ? s3 : SENT;
    int v4 = (sub + 32 < deg) ? s4 : SENT;
    int v5 = (sub + 40 < deg) ? s5 : SENT;

    // phase 1: only the ns needed gathers issue, all in flight
    float4 r0 = make_float4(0.f,0.f,0.f,0.f), r1 = r0, r2 = r0,
           r3 = r0, r4 = r0, r5 = r0;
    if (0 < ns) r0 = *(const float4*)(xs + (size_t)v0 * D + c8 * 8);
    if (1 < ns) r1 = *(const float4*)(xs + (size_t)v1 * D + c8 * 8);
    if (2 < ns) r2 = *(const float4*)(xs + (size_t)v2 * D + c8 * 8);
    if (3 < ns) r3 = *(const float4*)(xs + (size_t)v3 * D + c8 * 8);
    if (4 < ns) r4 = *(const float4*)(xs + (size_t)v4 * D + c8 * 8);
    if (5 < ns) r5 = *(const float4*)(xs + (size_t)v5 * D + c8 * 8);

    float di = rsqrtf((float)dc + 1.0f);   // +1 self-loop

    float4 a0 = make_float4(0.f, 0.f, 0.f, 0.f);
    float4 a1 = make_float4(0.f, 0.f, 0.f, 0.f);
    {
        float4 rr[7] = {r0, r1, r2, r3, r4, r5, xsr};
#pragma unroll
        for (int k = 0; k < 7; ++k) {
            const __half2* hp = (const __half2*)&rr[k];
            float2 p0 = __half22float2(hp[0]), p1 = __half22float2(hp[1]);
            float2 p2 = __half22float2(hp[2]), p3 = __half22float2(hp[3]);
            a0.x += p0.x; a0.y += p0.y; a0.z += p1.x; a0.w += p1.y;
            a1.x += p2.x; a1.y += p2.y; a1.z += p3.x; a1.w += p3.y;
        }
    }

    // reduce over the 8 subs
#pragma unroll
    for (int o = 8; o < 64; o <<= 1) {
        a0.x += __shfl_xor(a0.x, o, 64); a0.y += __shfl_xor(a0.y, o, 64);
        a0.z += __shfl_xor(a0.z, o, 64); a0.w += __shfl_xor(a0.w, o, 64);
        a1.x += __shfl_xor(a1.x, o, 64); a1.y += __shfl_xor(a1.y, o, 64);
        a1.z += __shfl_xor(a1.z, o, 64); a1.w += __shfl_xor(a1.w, o, 64);
    }

    const float4* bp = (const float4*)(b + c8 * 8);
    float4 b0 = bp[0], b1 = bp[1];

    float h[8];
    h[0] = x0.x + di * a0.x + b0.x;
    h[1] = x0.y + di * a0.y + b0.y;
    h[2] = x0.z + di * a0.z + b0.z;
    h[3] = x0.w + di * a0.w + b0.w;
    h[4] = x1.x + di * a1.x + b1.x;
    h[5] = x1.y + di * a1.y + b1.y;
    h[6] = x1.z + di * a1.z + b1.z;
    h[7] = x1.w + di * a1.w + b1.w;

    // LayerNorm: each column appears once per sub => divisor D*8 = 512
    float s_ = 0.f;
#pragma unroll
    for (int i = 0; i < 8; ++i) s_ += h[i];
#pragma unroll
    for (int o = 1; o < 64; o <<= 1) s_ += __shfl_xor(s_, o, 64);
    float mu = s_ * (1.0f / 512.0f);
    float v_ = 0.f;
    float dd[8];
#pragma unroll
    for (int i = 0; i < 8; ++i) { dd[i] = h[i] - mu; v_ += dd[i] * dd[i]; }
#pragma unroll
    for (int o = 1; o < 64; o <<= 1) v_ += __shfl_xor(v_, o, 64);
    float rstd = rsqrtf(v_ * (1.0f / 512.0f) + LN_EPS);

    if (sub == 0) {
        const float4* gp = (const float4*)(gamma + c8 * 8);
        const float4* ep = (const float4*)(beta + c8 * 8);
        float4 g0 = gp[0], g1 = gp[1];
        float4 e0 = ep[0], e1 = ep[1];
        float4 w0, w1;
        w0.x = fmaxf(dd[0] * rstd * g0.x + e0.x, 0.f);
        w0.y = fmaxf(dd[1] * rstd * g0.y + e0.y, 0.f);
        w0.z = fmaxf(dd[2] * rstd * g0.z + e0.z, 0.f);
        w0.w = fmaxf(dd[3] * rstd * g0.w + e0.w, 0.f);
        w1.x = fmaxf(dd[4] * rstd * g1.x + e1.x, 0.f);
        w1.y = fmaxf(dd[5] * rstd * g1.y + e1.y, 0.f);
        w1.z = fmaxf(dd[6] * rstd * g1.z + e1.z, 0.f);
        w1.w = fmaxf(dd[7] * rstd * g1.w + e1.w, 0.f);
        float4* op = (float4*)(out + (size_t)row * D + c8 * 8);
        op[0] = w0;
        op[1] = w1;
    }
}

extern "C" void kernel_launch(void* const* d_in, const int* in_sizes, int n_in,
                              void* d_out, int out_size, void* d_ws, size_t ws_size,
                              hipStream_t stream) {
    const float* x     = (const float*)d_in[0];
    const int*   ei    = (const int*)d_in[1];
    const float* W     = (const float*)d_in[2];
    const float* b     = (const float*)d_in[3];
    const float* gamma = (const float*)d_in[4];
    const float* beta  = (const float*)d_in[5];
    float* out = (float*)d_out;

    const int* src = ei;
    const int* dst = ei + N_EDGES;

    int*    cnt  = (int*)d_ws;                              // CNT_PAD int
    __half* xs   = (__half*)(cnt + CNT_PAD);                // XS_ROWS*D half
    u16*    H    = (u16*)(xs + (size_t)XS_ROWS * D);        // NCH2*50000 u16
    u16*    lpos = H + (size_t)NCH2 * N_NODES;              // E u16
    u16*    ssrc = lpos + N_EDGES;                          // N*CAP u16

    indep_k<<<HIST_NB + GEMM_NB, 256, 0, stream>>>(dst, lpos, H, x, W, xs);
    pref_scale_k<<<(N_NODES + 255) / 256, 256, 0, stream>>>(H, cnt, xs);
    scatter_k<<<SC_EB, 256, 0, stream>>>(src, dst, lpos, H, ssrc);
    agg_ln_k<<<(N_NODES + 3) / 4, 256, 0, stream>>>(x, xs, cnt, ssrc, b, gamma, beta, out);
}